// Round 10
// baseline (135.272 us; speedup 1.0000x reference)
//
#include <hip/hip_runtime.h>
#include <hip/hip_bf16.h>

typedef __attribute__((ext_vector_type(4))) float f32x4;
typedef __attribute__((ext_vector_type(8))) __bf16 bf16x8;
typedef __attribute__((ext_vector_type(8))) unsigned short u16x8;
typedef __attribute__((ext_vector_type(4))) unsigned short u16x4;
typedef __attribute__((ext_vector_type(2))) unsigned int u32x2;
typedef unsigned short u16;

#define DEV static __device__ __forceinline__

DEV u16 f2bf(float f){
  unsigned u = __builtin_bit_cast(unsigned, f);
  u += 0x7fff + ((u >> 16) & 1);            // RNE
  return (u16)(u >> 16);
}

DEV unsigned cvtpk(float lo, float hi){      // packed RNE f32->bf16 pair
  unsigned r;
  asm("v_cvt_pk_bf16_f32 %0, %1, %2" : "=v"(r) : "v"(lo), "v"(hi));
  return r;
}

DEV f32x4 mfma16(bf16x8 a, bf16x8 b, f32x4 c){
  return __builtin_amdgcn_mfma_f32_16x16x32_bf16(a, b, c, 0, 0, 0);
}

DEV void gload16(const void* g, void* l){
  __builtin_amdgcn_global_load_lds((const __attribute__((address_space(1))) void*)g,
                                   (__attribute__((address_space(3))) void*)l,
                                   16, 0, 0);
}

DEV float fexp2(float x){
#if __has_builtin(__builtin_amdgcn_exp2f)
  return __builtin_amdgcn_exp2f(x);
#else
  float r; asm("v_exp_f32 %0, %1" : "=v"(r) : "v"(x)); return r;
#endif
}

#define SCL 0.18033688011f   /* 0.125 * log2(e) */
#define THR 11.0f            /* defer-max threshold (log2 units) */
#define PLD 72               /* P row stride in u16 */

// ------------------------------------------------------------------
// fp32 -> bf16 conversion for the 4 weight matrices (1024x1024 each).
// ------------------------------------------------------------------
__global__ __launch_bounds__(256) void cvtW_k(
    const float* __restrict__ s0, const float* __restrict__ s1,
    const float* __restrict__ s2, const float* __restrict__ s3,
    u16* __restrict__ d0, u16* __restrict__ d1,
    u16* __restrict__ d2, u16* __restrict__ d3){
  const int y = blockIdx.y;
  const float* __restrict__ s = y==0?s0:y==1?s1:y==2?s2:s3;
  u16* __restrict__ d         = y==0?d0:y==1?d1:y==2?d2:d3;
  const int i = blockIdx.x*256 + threadIdx.x;   // 512*256 = 131072 = 1M/8
  f32x4 a = *(const f32x4*)&s[(size_t)i*8];
  f32x4 b = *(const f32x4*)&s[(size_t)i*8 + 4];
  u16x8 h;
  #pragma unroll
  for (int j = 0; j < 4; ++j){ h[j] = f2bf(a[j]); h[j+4] = f2bf(b[j]); }
  *(u16x8*)&d[(size_t)i*8] = h;
}

// ------------------------------------------------------------------
// Fragment readers from XOR-swizzled LDS tiles.
// Hs: bf16 [128][64], 16B granule swizzle: g ^= row&7.
// Fs: fp32 [128][64], 16B granule swizzle: g ^= row&15; cvt_pk to bf16.
// ------------------------------------------------------------------
DEV bf16x8 rdH(const u16* Hs, int r, int kc, int lhi, int l7){
  int gr = (kc*4 + lhi) ^ l7;
  return *(const bf16x8*)&Hs[r*64 + gr*8];
}

DEV bf16x8 rdF(const float* Fs, int r, int kc, int lhi, int l15){
  int g0 = kc*8 + lhi*2, g1 = g0 + 1;
  f32x4 a = *(const f32x4*)&Fs[r*64 + ((g0 ^ l15)*4)];
  f32x4 b = *(const f32x4*)&Fs[r*64 + ((g1 ^ l15)*4)];
  union { unsigned u[4]; bf16x8 v; } x;
  x.u[0] = cvtpk(a[0], a[1]);
  x.u[1] = cvtpk(a[2], a[3]);
  x.u[2] = cvtpk(b[0], b[1]);
  x.u[3] = cvtpk(b[2], b[3]);
  return x.v;
}

// ------------------------------------------------------------------
// QKV GEMM, fp32-X staged directly (no X pre-convert), BK=64,
// XCD-grouped block decode. z<2: C=X@W^T -> [B,H,N,64] (z0 scaled);
// z==2: C'=Wv@Xv^T -> V^T [B,H,64,N].
// ------------------------------------------------------------------
__global__ __launch_bounds__(256) void gemm_qkv2(
    const float* __restrict__ Xq, const float* __restrict__ Xk, const float* __restrict__ Xv,
    const u16* __restrict__ Wq, const u16* __restrict__ Wk, const u16* __restrict__ Wv,
    const float* __restrict__ Bq, const float* __restrict__ Bk, const float* __restrict__ Bv,
    u16* __restrict__ Oq, u16* __restrict__ Ok, u16* __restrict__ Ov){
  __shared__ float Fs[128*64];   // 32 KB fp32 operand tile
  __shared__ u16  Hs[128*64];    // 16 KB bf16 operand tile

  // XCD-grouped bijective decode: blocks sharing the fp32 panel land on
  // one XCD (f%8). 768 = 8 XCD * 12 panels * 8 bn.
  const int f = blockIdx.x;
  const int xc = f & 7, g = f >> 3;
  const int p  = xc*12 + (g >> 3);      // panel 0..95
  const int bn8 = g & 7;
  const int z = p >> 5, bm32 = p & 31;
  const bool vt = (z == 2);
  const int bm = vt ? bn8 : bm32;       // A-tile block
  const int bn = vt ? bm32 : bn8;       // B-tile block

  const float* __restrict__ Xz = z==0 ? Xq : z==1 ? Xk : Xv;
  const u16*  __restrict__ Wz  = z==0 ? Wq : z==1 ? Wk : Wv;
  const float* __restrict__ bias = z==0 ? Bq : z==1 ? Bk : Bv;
  u16* __restrict__ C = z==0 ? Oq : z==1 ? Ok : Ov;
  const float qs = (z==0) ? SCL : 1.0f;

  const int tid = threadIdx.x, lane = tid & 63, w = tid >> 6;
  const int wr = w >> 1, wc = w & 1;
  const int l16 = lane & 15, lhi = lane >> 4, l7 = l16 & 7;

  // staging (linear LDS dst = slot*16B; inverse-swizzled global source)
  const int frow = tid >> 4, fcol = ((tid & 15) ^ (frow & 15)) * 4;
  const int hrow = tid >> 3, hcol = ((tid & 7) ^ (hrow & 7)) * 8;
  const int fblk = vt ? bn : bm;        // rows of fp32 operand
  const int hblk = vt ? bm : bn;        // rows of bf16 operand
  const float* Fsrc = Xz + (size_t)(fblk*128 + frow)*1024 + fcol;
  const u16*  Hsrc  = Wz + (size_t)(hblk*128 + hrow)*1024 + hcol;

  f32x4 acc[4][4] = {};

  for (int k0 = 0; k0 < 1024; k0 += 64){
    __syncthreads();
    #pragma unroll
    for (int j = 0; j < 8; ++j)
      gload16(Fsrc + k0 + (size_t)j*16*1024, Fs + j*1024 + w*256);
    #pragma unroll
    for (int j = 0; j < 4; ++j)
      gload16(Hsrc + k0 + (size_t)j*32*1024, Hs + j*2048 + w*512);
    __syncthreads();

    #pragma unroll
    for (int kc = 0; kc < 2; ++kc){
      bf16x8 fa[4], fb[4];
      if (!vt){
        #pragma unroll
        for (int mi = 0; mi < 4; ++mi) fa[mi] = rdF(Fs, wr*64 + mi*16 + l16, kc, lhi, l16);
        #pragma unroll
        for (int nf = 0; nf < 4; ++nf) fb[nf] = rdH(Hs, wc*64 + nf*16 + l16, kc, lhi, l7);
      } else {
        #pragma unroll
        for (int mi = 0; mi < 4; ++mi) fa[mi] = rdH(Hs, wr*64 + mi*16 + l16, kc, lhi, l7);
        #pragma unroll
        for (int nf = 0; nf < 4; ++nf) fb[nf] = rdF(Fs, wc*64 + nf*16 + l16, kc, lhi, l16);
      }
      #pragma unroll
      for (int mi = 0; mi < 4; ++mi)
        #pragma unroll
        for (int nf = 0; nf < 4; ++nf)
          acc[mi][nf] = mfma16(fa[mi], fb[nf], acc[mi][nf]);
    }
  }

  #pragma unroll
  for (int mi = 0; mi < 4; ++mi){
    #pragma unroll
    for (int nf = 0; nf < 4; ++nf){
      int row0 = bm*128 + wr*64 + mi*16 + lhi*4;
      int col  = bn*128 + wc*64 + nf*16 + l16;
      float bc = bias[col];
      #pragma unroll
      for (int r = 0; r < 4; ++r){
        int row = row0 + r;
        float val = (acc[mi][nf][r] + (vt ? bias[row] : bc)) * qs;
        if (!vt){
          int b = row >> 11, n = row & 2047;
          int h = col >> 6,  dk = col & 63;
          C[(((size_t)(b*16 + h))*2048 + n)*64 + dk] = f2bf(val);
        } else {
          int h = row >> 6,  dk = row & 63;
          int b = col >> 11, n = col & 2047;
          C[(((size_t)(b*16 + h))*64 + dk)*2048 + n] = f2bf(val);
        }
      }
    }
  }
}

// ------------------------------------------------------------------
// O-projection GEMM: 64x128 tile, XCD-grouped decode (512 blocks).
// ------------------------------------------------------------------
__global__ __launch_bounds__(256) void gemm_o64(const u16* __restrict__ A,
                                                const u16* __restrict__ Bw,
                                                const float* __restrict__ bias,
                                                float* __restrict__ C){
  __shared__ u16 As[64*32];
  __shared__ u16 Bs[128*32];
  const int f = blockIdx.x;
  const int bm = (f & 7)*8 + ((f >> 3) >> 3);   // A-panel group per XCD
  const int bn = (f >> 3) & 7;
  const int tid  = threadIdx.x;
  const int lane = tid & 63, w = tid >> 6;
  const int wr = w >> 1, wc = w & 1;
  const int l16 = lane & 15, lhi = lane >> 4;

  const int srow = w*16 + (lane >> 2);
  const int scol = (lane & 3)*8;
  const u16* Asrc = A  + (size_t)(bm*64  + srow)*1024 + scol;
  const u16* Bsrc = Bw + (size_t)(bn*128 + srow)*1024 + scol;
  u16* Adst0 = As + w*512;
  u16* Bdst0 = Bs + w*512;

  f32x4 acc[2][4] = {};

  for (int k0 = 0; k0 < 1024; k0 += 32){
    __syncthreads();
    gload16(Asrc + k0,             Adst0);
    gload16(Bsrc + k0,             Bdst0);
    gload16(Bsrc + 64*1024 + k0,   Bdst0 + 2048);
    __syncthreads();

    bf16x8 af[2], bfr[4];
    #pragma unroll
    for (int mi = 0; mi < 2; ++mi)
      af[mi] = *(const bf16x8*)&As[(wr*32 + mi*16 + l16)*32 + lhi*8];
    #pragma unroll
    for (int nf = 0; nf < 4; ++nf)
      bfr[nf] = *(const bf16x8*)&Bs[(wc*64 + nf*16 + l16)*32 + lhi*8];
    #pragma unroll
    for (int mi = 0; mi < 2; ++mi)
      #pragma unroll
      for (int nf = 0; nf < 4; ++nf)
        acc[mi][nf] = mfma16(af[mi], bfr[nf], acc[mi][nf]);
  }

  #pragma unroll
  for (int mi = 0; mi < 2; ++mi){
    #pragma unroll
    for (int nf = 0; nf < 4; ++nf){
      int row0 = bm*64 + wr*32 + mi*16 + lhi*4;
      int col  = bn*128 + wc*64 + nf*16 + l16;
      float bv = bias[col];
      #pragma unroll
      for (int r = 0; r < 4; ++r)
        C[(size_t)(row0 + r)*1024 + col] = acc[mi][nf][r] + bv;
    }
  }
}

// ------------------------------------------------------------------
// Flash attention, software-pipelined (unchanged from r9).
// ------------------------------------------------------------------
DEV void sm_tile(int t, int qt, int q_abs,
                 const u16* __restrict__ Ksb, u16* __restrict__ PsW,
                 bf16x8 bq0, bf16x8 bq1,
                 f32x4* ctx, float& m_r, float& l_r,
                 int l16, int lhi, int lane, int swz){
  f32x4 s4[4] = {};
  #pragma unroll
  for (int nf = 0; nf < 4; ++nf){
    bf16x8 ak0 = *(const bf16x8*)&Ksb[(nf*16 + l16)*64 + ((lhi*8) ^ swz)];
    bf16x8 ak1 = *(const bf16x8*)&Ksb[(nf*16 + l16)*64 + ((32 + lhi*8) ^ swz)];
    s4[nf] = mfma16(ak0, bq0, s4[nf]);
    s4[nf] = mfma16(ak1, bq1, s4[nf]);
  }

  if (t == qt){
    #pragma unroll
    for (int nf = 0; nf < 4; ++nf)
      #pragma unroll
      for (int r = 0; r < 4; ++r){
        int kc = t*64 + nf*16 + lhi*4 + r;
        if (kc > q_abs) s4[nf][r] = -1.0e30f;
      }
  }

  float mt = fmaxf(
      fmaxf(fmaxf(fmaxf(s4[0][0],s4[0][1]), fmaxf(s4[0][2],s4[0][3])),
            fmaxf(fmaxf(s4[1][0],s4[1][1]), fmaxf(s4[1][2],s4[1][3]))),
      fmaxf(fmaxf(fmaxf(s4[2][0],s4[2][1]), fmaxf(s4[2][2],s4[2][3])),
            fmaxf(fmaxf(s4[3][0],s4[3][1]), fmaxf(s4[3][2],s4[3][3]))));
  mt = fmaxf(mt, __shfl_xor(mt, 16));
  mt = fmaxf(mt, __shfl_xor(mt, 32));

  if (!__all(mt <= m_r + THR)){
    float mn = fmaxf(m_r, mt);
    float sf = fexp2(m_r - mn);
    m_r = mn;
    l_r *= sf;
    float sfb[4];
    #pragma unroll
    for (int r = 0; r < 4; ++r)
      sfb[r] = __shfl(sf, (lane >> 4)*4 + r);
    #pragma unroll
    for (int dkf = 0; dkf < 4; ++dkf)
      #pragma unroll
      for (int r = 0; r < 4; ++r)
        ctx[dkf][r] *= sfb[r];
  }

  float lt = 0.f;
  u16* prow = PsW + l16*PLD;
  #pragma unroll
  for (int nf = 0; nf < 4; ++nf){
    float p0 = fexp2(s4[nf][0] - m_r);
    float p1 = fexp2(s4[nf][1] - m_r);
    float p2 = fexp2(s4[nf][2] - m_r);
    float p3 = fexp2(s4[nf][3] - m_r);
    lt += (p0 + p1) + (p2 + p3);
    unsigned w0 = __builtin_amdgcn_perm(__builtin_bit_cast(unsigned, p1),
                                        __builtin_bit_cast(unsigned, p0), 0x07060302u);
    unsigned w1 = __builtin_amdgcn_perm(__builtin_bit_cast(unsigned, p3),
                                        __builtin_bit_cast(unsigned, p2), 0x07060302u);
    u32x2 wp = {w0, w1};
    *(u32x2*)&prow[nf*16 + lhi*4] = wp;
  }
  lt += __shfl_xor(lt, 16);
  lt += __shfl_xor(lt, 32);
  l_r += lt;
}

DEV void pv_tile(const u16* __restrict__ Vsb, const u16* __restrict__ PsW,
                 f32x4* ctx, int l16, int lhi, int swz){
  const u16* prow = PsW + l16*PLD;
  __builtin_amdgcn_s_setprio(1);
  #pragma unroll
  for (int ks = 0; ks < 2; ++ks){
    bf16x8 pa = *(const bf16x8*)&prow[ks*32 + lhi*8];
    #pragma unroll
    for (int dkf = 0; dkf < 4; ++dkf){
      bf16x8 vb = *(const bf16x8*)&Vsb[(dkf*16 + l16)*64 + ((ks*32 + lhi*8) ^ swz)];
      ctx[dkf] = mfma16(pa, vb, ctx[dkf]);
    }
  }
  __builtin_amdgcn_s_setprio(0);
}

__global__ __launch_bounds__(256) void attn_k(const u16* __restrict__ Q,
                                              const u16* __restrict__ K,
                                              const u16* __restrict__ Vt,
                                              u16* __restrict__ CTX){
  __shared__ u16 Ks[2][64*64];
  __shared__ u16 Vs[2][64*64];
  __shared__ u16 Ps[4][2][16*PLD];
  const int tid  = threadIdx.x;
  const int lane = tid & 63, w = tid >> 6;
  const int l16 = lane & 15, lhi = lane >> 4;
  const int f  = blockIdx.x;
  const int bh = f & 31;
  const int qt = 31 - (f >> 5);
  const size_t base = (size_t)bh * 2048 * 64;
  const u16* Qb = Q  + base;
  const u16* Kb = K  + base;
  const u16* Vb = Vt + base;
  const int b = bh >> 4, h = bh & 15;

  const int s0 = tid, s1 = tid + 256;
  const int r0 = s0 >> 3, c0 = ((s0 & 7) ^ (r0 & 7))*8;
  const int r1 = s1 >> 3, c1 = ((s1 & 7) ^ (r1 & 7))*8;
  const u16* Ksrc0 = Kb + r0*64 + c0;
  const u16* Ksrc1 = Kb + r1*64 + c1;
  const u16* Vsrc0 = Vb + (size_t)r0*2048 + c0;
  const u16* Vsrc1 = Vb + (size_t)r1*2048 + c1;
  const int swz = (l16 & 7)*8;

  const int q_abs = qt*64 + w*16 + l16;
  bf16x8 bq0 = *(const bf16x8*)&Qb[(size_t)q_abs*64 + lhi*8];
  bf16x8 bq1 = *(const bf16x8*)&Qb[(size_t)q_abs*64 + 32 + lhi*8];

  f32x4 ctx[4] = {};
  float m_r = -3.0e38f, l_r = 0.f;
  u16* Ps0 = &Ps[w][0][0];
  u16* Ps1 = &Ps[w][1][0];

  gload16(Ksrc0, &Ks[0][s0*8]);  gload16(Ksrc1, &Ks[0][s1*8]);
  gload16(Vsrc0, &Vs[0][s0*8]);  gload16(Vsrc1, &Vs[0][s1*8]);
  __syncthreads();

  const int nt = qt + 1;
  for (int t = 0; t < nt; ++t){
    const int pb = t & 1;
    u16* PsC = pb ? Ps1 : Ps0;
    u16* PsP = pb ? Ps0 : Ps1;
    if (t + 1 < nt){
      gload16(Ksrc0 + (t+1)*4096, &Ks[pb^1][s0*8]);
      gload16(Ksrc1 + (t+1)*4096, &Ks[pb^1][s1*8]);
    }
    sm_tile(t, qt, q_abs, Ks[pb], PsC, bq0, bq1, ctx, m_r, l_r, l16, lhi, lane, swz);
    if (t > 0)
      pv_tile(Vs[pb^1], PsP, ctx, l16, lhi, swz);
    __syncthreads();
    if (t + 1 < nt){
      gload16(Vsrc0 + (size_t)(t+1)*64, &Vs[pb^1][s0*8]);
      gload16(Vsrc1 + (size_t)(t+1)*64, &Vs[pb^1][s1*8]);
    }
  }
  pv_tile(Vs[(nt-1)&1], (nt-1)&1 ? Ps1 : Ps0, ctx, l16, lhi, swz);

  float lf[4];
  #pragma unroll
  for (int r = 0; r < 4; ++r)
    lf[r] = __shfl(l_r, (lane >> 4)*4 + r);
  #pragma unroll
  for (int dkf = 0; dkf < 4; ++dkf)
    #pragma unroll
    for (int r = 0; r < 4; ++r){
      int q = qt*64 + w*16 + lhi*4 + r;
      CTX[((size_t)(b*2048 + q))*1024 + h*64 + dkf*16 + l16] = f2bf(ctx[dkf][r] / lf[r]);
    }
}

// ------------------------------------------------------------------
extern "C" void kernel_launch(void* const* d_in, const int* in_sizes, int n_in,
                              void* d_out, int out_size, void* d_ws, size_t ws_size,
                              hipStream_t stream){
  const float* q  = (const float*)d_in[0];
  const float* k  = (const float*)d_in[1];
  const float* v  = (const float*)d_in[2];
  const float* Wq = (const float*)d_in[4];  const float* bq = (const float*)d_in[5];
  const float* Wk = (const float*)d_in[6];  const float* bk = (const float*)d_in[7];
  const float* Wv = (const float*)d_in[8];  const float* bv = (const float*)d_in[9];
  const float* Wo = (const float*)d_in[10]; const float* bo = (const float*)d_in[11];
  float* out = (float*)d_out;
  dim3 blk(256);

  u16* Wqb = (u16*)d_ws;               // 4 x 1M u16 weights
  u16* Wkb = Wqb + 1048576;
  u16* Wvb = Wkb + 1048576;
  u16* Wob = Wvb + 1048576;
  u16* Qw  = Wob + 1048576;            // [B,H,N,64]
  u16* Kw  = Qw + 4194304;
  u16* Vw  = Kw + 4194304;             // V^T [B,H,64,N]
  u16* Cw  = Vw + 4194304;             // ctx [B,N,1024]

  cvtW_k<<<dim3(512, 4), blk, 0, stream>>>(Wq, Wk, Wv, Wo, Wqb, Wkb, Wvb, Wob);
  gemm_qkv2<<<dim3(768), blk, 0, stream>>>(q, k, v, Wqb, Wkb, Wvb,
                                           bq, bk, bv, Qw, Kw, Vw);
  attn_k<<<dim3(1024), blk, 0, stream>>>(Qw, Kw, Vw, Cw);
  gemm_o64<<<dim3(512), blk, 0, stream>>>(Cw, Wob, bo, out);
}

// Round 11
// 133.077 us; speedup vs baseline: 1.0165x; 1.0165x over previous
//
#include <hip/hip_runtime.h>
#include <hip/hip_bf16.h>

typedef __attribute__((ext_vector_type(4))) float f32x4;
typedef __attribute__((ext_vector_type(8))) __bf16 bf16x8;
typedef __attribute__((ext_vector_type(8))) unsigned short u16x8;
typedef __attribute__((ext_vector_type(4))) unsigned short u16x4;
typedef __attribute__((ext_vector_type(2))) unsigned int u32x2;
typedef unsigned short u16;

#define DEV static __device__ __forceinline__

DEV u16 f2bf(float f){
  unsigned u = __builtin_bit_cast(unsigned, f);
  u += 0x7fff + ((u >> 16) & 1);            // RNE
  return (u16)(u >> 16);
}

DEV f32x4 mfma16(bf16x8 a, bf16x8 b, f32x4 c){
  return __builtin_amdgcn_mfma_f32_16x16x32_bf16(a, b, c, 0, 0, 0);
}

DEV void gload16(const void* g, void* l){
  __builtin_amdgcn_global_load_lds((const __attribute__((address_space(1))) void*)g,
                                   (__attribute__((address_space(3))) void*)l,
                                   16, 0, 0);
}

DEV float fexp2(float x){
#if __has_builtin(__builtin_amdgcn_exp2f)
  return __builtin_amdgcn_exp2f(x);
#else
  float r; asm("v_exp_f32 %0, %1" : "=v"(r) : "v"(x)); return r;
#endif
}

#define SCL 0.18033688011f   /* 0.125 * log2(e) */
#define THR 11.0f            /* defer-max threshold (log2 units) */
#define PLD 72               /* P row stride in u16 */

// ------------------------------------------------------------------
// fp32 -> bf16 conversion: y 0-2 = X (4096x1024), y 3-6 = W (1024x1024).
// ------------------------------------------------------------------
__global__ __launch_bounds__(256) void cvt_k(
    const float* __restrict__ s0, const float* __restrict__ s1,
    const float* __restrict__ s2, const float* __restrict__ s3,
    const float* __restrict__ s4, const float* __restrict__ s5,
    const float* __restrict__ s6,
    u16* __restrict__ d0, u16* __restrict__ d1, u16* __restrict__ d2,
    u16* __restrict__ d3, u16* __restrict__ d4, u16* __restrict__ d5,
    u16* __restrict__ d6){
  const int y = blockIdx.y;
  const float* __restrict__ s = y==0?s0:y==1?s1:y==2?s2:y==3?s3:y==4?s4:y==5?s5:s6;
  u16* __restrict__ d         = y==0?d0:y==1?d1:y==2?d2:y==3?d3:y==4?d4:y==5?d5:d6;
  const int n8 = (y < 3) ? (4096*1024/8) : (1024*1024/8);
  for (int i = blockIdx.x*256 + threadIdx.x; i < n8; i += gridDim.x*256){
    f32x4 a = *(const f32x4*)&s[(size_t)i*8];
    f32x4 b = *(const f32x4*)&s[(size_t)i*8 + 4];
    u16x8 h;
    #pragma unroll
    for (int j = 0; j < 4; ++j){ h[j] = f2bf(a[j]); h[j+4] = f2bf(b[j]); }
    *(u16x8*)&d[(size_t)i*8] = h;
  }
}

// ------------------------------------------------------------------
// QKV GEMM, m97 geometry: 128x128 tile, BK=64, bf16 both operands,
// LDS [128][64] u16 with 16B-granule XOR swizzle (g ^= row&7) applied
// via pre-swizzled global_load_lds sources; swizzled b128 reads ->
// ~2-way (free) conflicts. XCD-grouped block decode (panel-per-XCD).
// z<2: C = X@W^T -> [B,H,N,64] (z==0 scaled by SCL);
// z==2: C' = Wv@Xv^T -> V^T [B,H,64,N].
// ------------------------------------------------------------------
DEV bf16x8 rdS(const u16* T, int r, int kc, int lhi){
  int gr = (kc*4 + lhi) ^ (r & 7);
  return *(const bf16x8*)&T[r*64 + gr*8];
}

__global__ __launch_bounds__(256) void gemm_qkv3(
    const u16* __restrict__ Xq, const u16* __restrict__ Xk, const u16* __restrict__ Xv,
    const u16* __restrict__ Wq, const u16* __restrict__ Wk, const u16* __restrict__ Wv,
    const float* __restrict__ Bq, const float* __restrict__ Bk, const float* __restrict__ Bv,
    u16* __restrict__ Oq, u16* __restrict__ Ok, u16* __restrict__ Ov){
  __shared__ u16 As[128*64];   // 16 KB
  __shared__ u16 Bs[128*64];   // 16 KB

  // XCD-grouped bijective decode: 768 = 8 XCD * 12 panels * 8 bn.
  const int f = blockIdx.x;
  const int xc = f & 7, g = f >> 3;
  const int p  = xc*12 + (g >> 3);      // panel 0..95  ({z, bm32})
  const int bn8 = g & 7;
  const int z = p >> 5, bm32 = p & 31;
  const bool vt = (z == 2);
  const int bm = vt ? bn8 : bm32;
  const int bn = vt ? bm32 : bn8;

  const u16* __restrict__ A    = z==0 ? Xq : z==1 ? Xk : Wv;
  const u16* __restrict__ Bw   = z==0 ? Wq : z==1 ? Wk : Xv;
  const float* __restrict__ bias = z==0 ? Bq : z==1 ? Bk : Bv;
  u16* __restrict__ C = z==0 ? Oq : z==1 ? Ok : Ov;
  const float qs = (z==0) ? SCL : 1.0f;

  const int tid = threadIdx.x, lane = tid & 63, w = tid >> 6;
  const int wr = w >> 1, wc = w & 1;
  const int l16 = lane & 15, lhi = lane >> 4;

  // staging: slot s (0..1023) -> row=s>>3, LDS granule s&7,
  // global granule (s&7)^(row&7). 4 slots/thread/operand.
  const u16* Asrc[4];
  const u16* Bsrc[4];
  #pragma unroll
  for (int j = 0; j < 4; ++j){
    int s = tid + j*256;
    int row = s >> 3;
    int col = ((s & 7) ^ (row & 7)) * 8;
    Asrc[j] = A  + (size_t)(bm*128 + row)*1024 + col;
    Bsrc[j] = Bw + (size_t)(bn*128 + row)*1024 + col;
  }

  f32x4 acc[4][4] = {};

  for (int k0 = 0; k0 < 1024; k0 += 64){
    __syncthreads();
    #pragma unroll
    for (int j = 0; j < 4; ++j)
      gload16(Asrc[j] + k0, As + (tid + j*256)*8);
    #pragma unroll
    for (int j = 0; j < 4; ++j)
      gload16(Bsrc[j] + k0, Bs + (tid + j*256)*8);
    __syncthreads();

    #pragma unroll
    for (int kc = 0; kc < 2; ++kc){
      bf16x8 af[4], bfr[4];
      #pragma unroll
      for (int mi = 0; mi < 4; ++mi)
        af[mi] = rdS(As, wr*64 + mi*16 + l16, kc, lhi);
      #pragma unroll
      for (int nf = 0; nf < 4; ++nf)
        bfr[nf] = rdS(Bs, wc*64 + nf*16 + l16, kc, lhi);
      #pragma unroll
      for (int mi = 0; mi < 4; ++mi)
        #pragma unroll
        for (int nf = 0; nf < 4; ++nf)
          acc[mi][nf] = mfma16(af[mi], bfr[nf], acc[mi][nf]);
    }
  }

  #pragma unroll
  for (int mi = 0; mi < 4; ++mi){
    #pragma unroll
    for (int nf = 0; nf < 4; ++nf){
      int row0 = bm*128 + wr*64 + mi*16 + lhi*4;
      int col  = bn*128 + wc*64 + nf*16 + l16;
      float bc = bias[col];
      #pragma unroll
      for (int r = 0; r < 4; ++r){
        int row = row0 + r;
        float val = (acc[mi][nf][r] + (vt ? bias[row] : bc)) * qs;
        if (!vt){
          int b = row >> 11, n = row & 2047;
          int h = col >> 6,  dk = col & 63;
          C[(((size_t)(b*16 + h))*2048 + n)*64 + dk] = f2bf(val);
        } else {
          int h = row >> 6,  dk = row & 63;
          int b = col >> 11, n = col & 2047;
          C[(((size_t)(b*16 + h))*64 + dk)*2048 + n] = f2bf(val);
        }
      }
    }
  }
}

// ------------------------------------------------------------------
// O-projection GEMM: 64x128 tile, XCD-grouped decode (512 blocks).
// ------------------------------------------------------------------
__global__ __launch_bounds__(256) void gemm_o64(const u16* __restrict__ A,
                                                const u16* __restrict__ Bw,
                                                const float* __restrict__ bias,
                                                float* __restrict__ C){
  __shared__ u16 As[64*32];
  __shared__ u16 Bs[128*32];
  const int f = blockIdx.x;
  const int bm = (f & 7)*8 + ((f >> 3) >> 3);
  const int bn = (f >> 3) & 7;
  const int tid  = threadIdx.x;
  const int lane = tid & 63, w = tid >> 6;
  const int wr = w >> 1, wc = w & 1;
  const int l16 = lane & 15, lhi = lane >> 4;

  const int srow = w*16 + (lane >> 2);
  const int scol = (lane & 3)*8;
  const u16* Asrc = A  + (size_t)(bm*64  + srow)*1024 + scol;
  const u16* Bsrc = Bw + (size_t)(bn*128 + srow)*1024 + scol;
  u16* Adst0 = As + w*512;
  u16* Bdst0 = Bs + w*512;

  f32x4 acc[2][4] = {};

  for (int k0 = 0; k0 < 1024; k0 += 32){
    __syncthreads();
    gload16(Asrc + k0,             Adst0);
    gload16(Bsrc + k0,             Bdst0);
    gload16(Bsrc + 64*1024 + k0,   Bdst0 + 2048);
    __syncthreads();

    bf16x8 af[2], bfr[4];
    #pragma unroll
    for (int mi = 0; mi < 2; ++mi)
      af[mi] = *(const bf16x8*)&As[(wr*32 + mi*16 + l16)*32 + lhi*8];
    #pragma unroll
    for (int nf = 0; nf < 4; ++nf)
      bfr[nf] = *(const bf16x8*)&Bs[(wc*64 + nf*16 + l16)*32 + lhi*8];
    #pragma unroll
    for (int mi = 0; mi < 2; ++mi)
      #pragma unroll
      for (int nf = 0; nf < 4; ++nf)
        acc[mi][nf] = mfma16(af[mi], bfr[nf], acc[mi][nf]);
  }

  #pragma unroll
  for (int mi = 0; mi < 2; ++mi){
    #pragma unroll
    for (int nf = 0; nf < 4; ++nf){
      int row0 = bm*64 + wr*32 + mi*16 + lhi*4;
      int col  = bn*128 + wc*64 + nf*16 + l16;
      float bv = bias[col];
      #pragma unroll
      for (int r = 0; r < 4; ++r)
        C[(size_t)(row0 + r)*1024 + col] = acc[mi][nf][r] + bv;
    }
  }
}

// ------------------------------------------------------------------
// Flash attention, software-pipelined (unchanged from r9).
// ------------------------------------------------------------------
DEV void sm_tile(int t, int qt, int q_abs,
                 const u16* __restrict__ Ksb, u16* __restrict__ PsW,
                 bf16x8 bq0, bf16x8 bq1,
                 f32x4* ctx, float& m_r, float& l_r,
                 int l16, int lhi, int lane, int swz){
  f32x4 s4[4] = {};
  #pragma unroll
  for (int nf = 0; nf < 4; ++nf){
    bf16x8 ak0 = *(const bf16x8*)&Ksb[(nf*16 + l16)*64 + ((lhi*8) ^ swz)];
    bf16x8 ak1 = *(const bf16x8*)&Ksb[(nf*16 + l16)*64 + ((32 + lhi*8) ^ swz)];
    s4[nf] = mfma16(ak0, bq0, s4[nf]);
    s4[nf] = mfma16(ak1, bq1, s4[nf]);
  }

  if (t == qt){
    #pragma unroll
    for (int nf = 0; nf < 4; ++nf)
      #pragma unroll
      for (int r = 0; r < 4; ++r){
        int kc = t*64 + nf*16 + lhi*4 + r;
        if (kc > q_abs) s4[nf][r] = -1.0e30f;
      }
  }

  float mt = fmaxf(
      fmaxf(fmaxf(fmaxf(s4[0][0],s4[0][1]), fmaxf(s4[0][2],s4[0][3])),
            fmaxf(fmaxf(s4[1][0],s4[1][1]), fmaxf(s4[1][2],s4[1][3]))),
      fmaxf(fmaxf(fmaxf(s4[2][0],s4[2][1]), fmaxf(s4[2][2],s4[2][3])),
            fmaxf(fmaxf(s4[3][0],s4[3][1]), fmaxf(s4[3][2],s4[3][3]))));
  mt = fmaxf(mt, __shfl_xor(mt, 16));
  mt = fmaxf(mt, __shfl_xor(mt, 32));

  if (!__all(mt <= m_r + THR)){
    float mn = fmaxf(m_r, mt);
    float sf = fexp2(m_r - mn);
    m_r = mn;
    l_r *= sf;
    float sfb[4];
    #pragma unroll
    for (int r = 0; r < 4; ++r)
      sfb[r] = __shfl(sf, (lane >> 4)*4 + r);
    #pragma unroll
    for (int dkf = 0; dkf < 4; ++dkf)
      #pragma unroll
      for (int r = 0; r < 4; ++r)
        ctx[dkf][r] *= sfb[r];
  }

  float lt = 0.f;
  u16* prow = PsW + l16*PLD;
  #pragma unroll
  for (int nf = 0; nf < 4; ++nf){
    float p0 = fexp2(s4[nf][0] - m_r);
    float p1 = fexp2(s4[nf][1] - m_r);
    float p2 = fexp2(s4[nf][2] - m_r);
    float p3 = fexp2(s4[nf][3] - m_r);
    lt += (p0 + p1) + (p2 + p3);
    unsigned w0 = __builtin_amdgcn_perm(__builtin_bit_cast(unsigned, p1),
                                        __builtin_bit_cast(unsigned, p0), 0x07060302u);
    unsigned w1 = __builtin_amdgcn_perm(__builtin_bit_cast(unsigned, p3),
                                        __builtin_bit_cast(unsigned, p2), 0x07060302u);
    u32x2 wp = {w0, w1};
    *(u32x2*)&prow[nf*16 + lhi*4] = wp;
  }
  lt += __shfl_xor(lt, 16);
  lt += __shfl_xor(lt, 32);
  l_r += lt;
}

DEV void pv_tile(const u16* __restrict__ Vsb, const u16* __restrict__ PsW,
                 f32x4* ctx, int l16, int lhi, int swz){
  const u16* prow = PsW + l16*PLD;
  __builtin_amdgcn_s_setprio(1);
  #pragma unroll
  for (int ks = 0; ks < 2; ++ks){
    bf16x8 pa = *(const bf16x8*)&prow[ks*32 + lhi*8];
    #pragma unroll
    for (int dkf = 0; dkf < 4; ++dkf){
      bf16x8 vb = *(const bf16x8*)&Vsb[(dkf*16 + l16)*64 + ((ks*32 + lhi*8) ^ swz)];
      ctx[dkf] = mfma16(pa, vb, ctx[dkf]);
    }
  }
  __builtin_amdgcn_s_setprio(0);
}

__global__ __launch_bounds__(256) void attn_k(const u16* __restrict__ Q,
                                              const u16* __restrict__ K,
                                              const u16* __restrict__ Vt,
                                              u16* __restrict__ CTX){
  __shared__ u16 Ks[2][64*64];
  __shared__ u16 Vs[2][64*64];
  __shared__ u16 Ps[4][2][16*PLD];
  const int tid  = threadIdx.x;
  const int lane = tid & 63, w = tid >> 6;
  const int l16 = lane & 15, lhi = lane >> 4;
  const int f  = blockIdx.x;
  const int bh = f & 31;
  const int qt = 31 - (f >> 5);
  const size_t base = (size_t)bh * 2048 * 64;
  const u16* Qb = Q  + base;
  const u16* Kb = K  + base;
  const u16* Vb = Vt + base;
  const int b = bh >> 4, h = bh & 15;

  const int s0 = tid, s1 = tid + 256;
  const int r0 = s0 >> 3, c0 = ((s0 & 7) ^ (r0 & 7))*8;
  const int r1 = s1 >> 3, c1 = ((s1 & 7) ^ (r1 & 7))*8;
  const u16* Ksrc0 = Kb + r0*64 + c0;
  const u16* Ksrc1 = Kb + r1*64 + c1;
  const u16* Vsrc0 = Vb + (size_t)r0*2048 + c0;
  const u16* Vsrc1 = Vb + (size_t)r1*2048 + c1;
  const int swz = (l16 & 7)*8;

  const int q_abs = qt*64 + w*16 + l16;
  bf16x8 bq0 = *(const bf16x8*)&Qb[(size_t)q_abs*64 + lhi*8];
  bf16x8 bq1 = *(const bf16x8*)&Qb[(size_t)q_abs*64 + 32 + lhi*8];

  f32x4 ctx[4] = {};
  float m_r = -3.0e38f, l_r = 0.f;
  u16* Ps0 = &Ps[w][0][0];
  u16* Ps1 = &Ps[w][1][0];

  gload16(Ksrc0, &Ks[0][s0*8]);  gload16(Ksrc1, &Ks[0][s1*8]);
  gload16(Vsrc0, &Vs[0][s0*8]);  gload16(Vsrc1, &Vs[0][s1*8]);
  __syncthreads();

  const int nt = qt + 1;
  for (int t = 0; t < nt; ++t){
    const int pb = t & 1;
    u16* PsC = pb ? Ps1 : Ps0;
    u16* PsP = pb ? Ps0 : Ps1;
    if (t + 1 < nt){
      gload16(Ksrc0 + (t+1)*4096, &Ks[pb^1][s0*8]);
      gload16(Ksrc1 + (t+1)*4096, &Ks[pb^1][s1*8]);
    }
    sm_tile(t, qt, q_abs, Ks[pb], PsC, bq0, bq1, ctx, m_r, l_r, l16, lhi, lane, swz);
    if (t > 0)
      pv_tile(Vs[pb^1], PsP, ctx, l16, lhi, swz);
    __syncthreads();
    if (t + 1 < nt){
      gload16(Vsrc0 + (size_t)(t+1)*64, &Vs[pb^1][s0*8]);
      gload16(Vsrc1 + (size_t)(t+1)*64, &Vs[pb^1][s1*8]);
    }
  }
  pv_tile(Vs[(nt-1)&1], (nt-1)&1 ? Ps1 : Ps0, ctx, l16, lhi, swz);

  float lf[4];
  #pragma unroll
  for (int r = 0; r < 4; ++r)
    lf[r] = __shfl(l_r, (lane >> 4)*4 + r);
  #pragma unroll
  for (int dkf = 0; dkf < 4; ++dkf)
    #pragma unroll
    for (int r = 0; r < 4; ++r){
      int q = qt*64 + w*16 + lhi*4 + r;
      CTX[((size_t)(b*2048 + q))*1024 + h*64 + dkf*16 + l16] = f2bf(ctx[dkf][r] / lf[r]);
    }
}

// ------------------------------------------------------------------
extern "C" void kernel_launch(void* const* d_in, const int* in_sizes, int n_in,
                              void* d_out, int out_size, void* d_ws, size_t ws_size,
                              hipStream_t stream){
  const float* q  = (const float*)d_in[0];
  const float* k  = (const float*)d_in[1];
  const float* v  = (const float*)d_in[2];
  const float* Wq = (const float*)d_in[4];  const float* bq = (const float*)d_in[5];
  const float* Wk = (const float*)d_in[6];  const float* bk = (const float*)d_in[7];
  const float* Wv = (const float*)d_in[8];  const float* bv = (const float*)d_in[9];
  const float* Wo = (const float*)d_in[10]; const float* bo = (const float*)d_in[11];
  float* out = (float*)d_out;
  dim3 blk(256);

  // 56 MB layout (proven fits): 4 W (2MB each) + 3 X (8MB) + Q/K/V (8MB);
  // ctx aliases Xq (dead after QKV GEMM).
  u16* Wqb = (u16*)d_ws;
  u16* Wkb = Wqb + 1048576;
  u16* Wvb = Wkb + 1048576;
  u16* Wob = Wvb + 1048576;
  u16* Xqb = Wob + 1048576;
  u16* Xkb = Xqb + 4194304;
  u16* Xvb = Xkb + 4194304;
  u16* Qw  = Xvb + 4194304;
  u16* Kw  = Qw + 4194304;
  u16* Vw  = Kw + 4194304;             // V^T [B,H,64,N]
  u16* Cw  = Xqb;                      // reuse

  cvt_k<<<dim3(512, 7), blk, 0, stream>>>(q, k, v, Wq, Wk, Wv, Wo,
                                          Xqb, Xkb, Xvb, Wqb, Wkb, Wvb, Wob);
  gemm_qkv3<<<dim3(768), blk, 0, stream>>>(Xqb, Xkb, Xvb, Wqb, Wkb, Wvb,
                                           bq, bk, bv, Qw, Kw, Vw);
  attn_k<<<dim3(1024), blk, 0, stream>>>(Qw, Kw, Vw, Cw);
  gemm_o64<<<dim3(512), blk, 0, stream>>>(Cw, Wob, bo, out);
}

// Round 12
// 131.139 us; speedup vs baseline: 1.0315x; 1.0148x over previous
//
#include <hip/hip_runtime.h>
#include <hip/hip_bf16.h>

typedef __attribute__((ext_vector_type(4))) float f32x4;
typedef __attribute__((ext_vector_type(8))) __bf16 bf16x8;
typedef __attribute__((ext_vector_type(8))) unsigned short u16x8;
typedef __attribute__((ext_vector_type(4))) unsigned short u16x4;
typedef __attribute__((ext_vector_type(2))) unsigned int u32x2;
typedef unsigned short u16;

#define DEV static __device__ __forceinline__

DEV u16 f2bf(float f){
  unsigned u = __builtin_bit_cast(unsigned, f);
  u += 0x7fff + ((u >> 16) & 1);            // RNE
  return (u16)(u >> 16);
}

DEV f32x4 mfma16(bf16x8 a, bf16x8 b, f32x4 c){
  return __builtin_amdgcn_mfma_f32_16x16x32_bf16(a, b, c, 0, 0, 0);
}

DEV void gload16(const void* g, void* l){
  __builtin_amdgcn_global_load_lds((const __attribute__((address_space(1))) void*)g,
                                   (__attribute__((address_space(3))) void*)l,
                                   16, 0, 0);
}

DEV float fexp2(float x){
#if __has_builtin(__builtin_amdgcn_exp2f)
  return __builtin_amdgcn_exp2f(x);
#else
  float r; asm("v_exp_f32 %0, %1" : "=v"(r) : "v"(x)); return r;
#endif
}

#define SCL 0.18033688011f   /* 0.125 * log2(e) */
#define THR 11.0f            /* defer-max threshold (log2 units) */
#define PLD 72               /* P row stride in u16 */

// ------------------------------------------------------------------
// fp32 -> bf16 conversion: y 0-2 = X (4096x1024), y 3-6 = W (1024x1024).
// ------------------------------------------------------------------
__global__ __launch_bounds__(256) void cvt_k(
    const float* __restrict__ s0, const float* __restrict__ s1,
    const float* __restrict__ s2, const float* __restrict__ s3,
    const float* __restrict__ s4, const float* __restrict__ s5,
    const float* __restrict__ s6,
    u16* __restrict__ d0, u16* __restrict__ d1, u16* __restrict__ d2,
    u16* __restrict__ d3, u16* __restrict__ d4, u16* __restrict__ d5,
    u16* __restrict__ d6){
  const int y = blockIdx.y;
  const float* __restrict__ s = y==0?s0:y==1?s1:y==2?s2:y==3?s3:y==4?s4:y==5?s5:s6;
  u16* __restrict__ d         = y==0?d0:y==1?d1:y==2?d2:y==3?d3:y==4?d4:y==5?d5:d6;
  const int n8 = (y < 3) ? (4096*1024/8) : (1024*1024/8);
  for (int i = blockIdx.x*256 + threadIdx.x; i < n8; i += gridDim.x*256){
    f32x4 a = *(const f32x4*)&s[(size_t)i*8];
    f32x4 b = *(const f32x4*)&s[(size_t)i*8 + 4];
    u16x8 h;
    #pragma unroll
    for (int j = 0; j < 4; ++j){ h[j] = f2bf(a[j]); h[j+4] = f2bf(b[j]); }
    *(u16x8*)&d[(size_t)i*8] = h;
  }
}

// ------------------------------------------------------------------
// QKV GEMM: exact r9 structure (128x128 tile, BK=32, linear LDS,
// grid (8,32,3)) + T3-minimal pipeline: double-buffered LDS,
// stage-ahead issue, ONE barrier per K-step (load latency hides
// under current-tile compute instead of being drained cold).
// z<2: C = X@W^T -> [B,H,N,64] (z==0 scaled by SCL);
// z==2: A=Wv, B=Xv -> V^T [B,H,64,N].
// ------------------------------------------------------------------
__global__ __launch_bounds__(256) void gemm_bt(
    const u16* __restrict__ A0, const u16* __restrict__ A1, const u16* __restrict__ A2,
    const u16* __restrict__ B0, const u16* __restrict__ B1, const u16* __restrict__ B2,
    const float* __restrict__ e0, const float* __restrict__ e1, const float* __restrict__ e2,
    u16* __restrict__ C0, u16* __restrict__ C1, u16* __restrict__ C2){
  __shared__ u16 As[2][128*32];
  __shared__ u16 Bs[2][128*32];
  const int z = blockIdx.z;
  const u16* __restrict__ A    = z==0 ? A0 : z==1 ? A1 : A2;
  const u16* __restrict__ Bw   = z==0 ? B0 : z==1 ? B1 : B2;
  const float* __restrict__ bias = z==0 ? e0 : z==1 ? e1 : e2;
  u16* __restrict__ C          = z==0 ? C0 : z==1 ? C1 : C2;
  const bool vt = (z == 2);
  const float qs = (z == 0) ? SCL : 1.0f;

  const int tid  = threadIdx.x;
  const int lane = tid & 63, w = tid >> 6;
  const int wr = w >> 1, wc = w & 1;
  const int l16 = lane & 15, lhi = lane >> 4;
  const int bm = vt ? blockIdx.x : blockIdx.y;
  const int bn = vt ? blockIdx.y : blockIdx.x;

  const int srow = w*16 + (lane >> 2);
  const int scol = (lane & 3)*8;
  const u16* Asrc = A  + (size_t)(bm*128 + srow)*1024 + scol;
  const u16* Bsrc = Bw + (size_t)(bn*128 + srow)*1024 + scol;
  const int d0 = w*512;

  f32x4 acc[4][4] = {};

  // prologue: stage K-step 0 into buffer 0
  gload16(Asrc,             &As[0][d0]);
  gload16(Asrc + 64*1024,   &As[0][d0 + 2048]);
  gload16(Bsrc,             &Bs[0][d0]);
  gload16(Bsrc + 64*1024,   &Bs[0][d0 + 2048]);
  __syncthreads();

  for (int t = 0; t < 32; ++t){
    const int cur = t & 1, nxt = cur ^ 1;
    if (t < 31){
      const int k1 = (t + 1)*32;
      gload16(Asrc + k1,           &As[nxt][d0]);
      gload16(Asrc + 64*1024 + k1, &As[nxt][d0 + 2048]);
      gload16(Bsrc + k1,           &Bs[nxt][d0]);
      gload16(Bsrc + 64*1024 + k1, &Bs[nxt][d0 + 2048]);
    }
    bf16x8 af[4], bfr[4];
    #pragma unroll
    for (int mi = 0; mi < 4; ++mi)
      af[mi] = *(const bf16x8*)&As[cur][(wr*64 + mi*16 + l16)*32 + lhi*8];
    #pragma unroll
    for (int nf = 0; nf < 4; ++nf)
      bfr[nf] = *(const bf16x8*)&Bs[cur][(wc*64 + nf*16 + l16)*32 + lhi*8];
    #pragma unroll
    for (int mi = 0; mi < 4; ++mi)
      #pragma unroll
      for (int nf = 0; nf < 4; ++nf)
        acc[mi][nf] = mfma16(af[mi], bfr[nf], acc[mi][nf]);
    __syncthreads();
  }

  #pragma unroll
  for (int mi = 0; mi < 4; ++mi){
    #pragma unroll
    for (int nf = 0; nf < 4; ++nf){
      int row0 = bm*128 + wr*64 + mi*16 + lhi*4;
      int col  = bn*128 + wc*64 + nf*16 + l16;
      float bc = bias[col];
      #pragma unroll
      for (int r = 0; r < 4; ++r){
        int row = row0 + r;
        float val = (acc[mi][nf][r] + (vt ? bias[row] : bc)) * qs;
        if (!vt){
          int b = row >> 11, n = row & 2047;
          int h = col >> 6,  dk = col & 63;
          C[(((size_t)(b*16 + h))*2048 + n)*64 + dk] = f2bf(val);
        } else {
          int h = row >> 6,  dk = row & 63;
          int b = col >> 11, n = col & 2047;
          C[(((size_t)(b*16 + h))*64 + dk)*2048 + n] = f2bf(val);
        }
      }
    }
  }
}

// ------------------------------------------------------------------
// O-projection GEMM: 64x128 tile, grid (8,64), same T3-minimal dbuf.
// ------------------------------------------------------------------
__global__ __launch_bounds__(256) void gemm_o64(const u16* __restrict__ A,
                                                const u16* __restrict__ Bw,
                                                const float* __restrict__ bias,
                                                float* __restrict__ C){
  __shared__ u16 As[2][64*32];
  __shared__ u16 Bs[2][128*32];
  const int tid  = threadIdx.x;
  const int lane = tid & 63, w = tid >> 6;
  const int wr = w >> 1, wc = w & 1;
  const int l16 = lane & 15, lhi = lane >> 4;
  const int bm = blockIdx.y, bn = blockIdx.x;

  const int srow = w*16 + (lane >> 2);
  const int scol = (lane & 3)*8;
  const u16* Asrc = A  + (size_t)(bm*64  + srow)*1024 + scol;
  const u16* Bsrc = Bw + (size_t)(bn*128 + srow)*1024 + scol;
  const int d0 = w*512;

  f32x4 acc[2][4] = {};

  gload16(Asrc,           &As[0][d0]);
  gload16(Bsrc,           &Bs[0][d0]);
  gload16(Bsrc + 64*1024, &Bs[0][d0 + 2048]);
  __syncthreads();

  for (int t = 0; t < 32; ++t){
    const int cur = t & 1, nxt = cur ^ 1;
    if (t < 31){
      const int k1 = (t + 1)*32;
      gload16(Asrc + k1,           &As[nxt][d0]);
      gload16(Bsrc + k1,           &Bs[nxt][d0]);
      gload16(Bsrc + 64*1024 + k1, &Bs[nxt][d0 + 2048]);
    }
    bf16x8 af[2], bfr[4];
    #pragma unroll
    for (int mi = 0; mi < 2; ++mi)
      af[mi] = *(const bf16x8*)&As[cur][(wr*32 + mi*16 + l16)*32 + lhi*8];
    #pragma unroll
    for (int nf = 0; nf < 4; ++nf)
      bfr[nf] = *(const bf16x8*)&Bs[cur][(wc*64 + nf*16 + l16)*32 + lhi*8];
    #pragma unroll
    for (int mi = 0; mi < 2; ++mi)
      #pragma unroll
      for (int nf = 0; nf < 4; ++nf)
        acc[mi][nf] = mfma16(af[mi], bfr[nf], acc[mi][nf]);
    __syncthreads();
  }

  #pragma unroll
  for (int mi = 0; mi < 2; ++mi){
    #pragma unroll
    for (int nf = 0; nf < 4; ++nf){
      int row0 = bm*64 + wr*32 + mi*16 + lhi*4;
      int col  = bn*128 + wc*64 + nf*16 + l16;
      float bv = bias[col];
      #pragma unroll
      for (int r = 0; r < 4; ++r)
        C[(size_t)(row0 + r)*1024 + col] = acc[mi][nf][r] + bv;
    }
  }
}

// ------------------------------------------------------------------
// Flash attention, software-pipelined (unchanged from r9).
// ------------------------------------------------------------------
DEV void sm_tile(int t, int qt, int q_abs,
                 const u16* __restrict__ Ksb, u16* __restrict__ PsW,
                 bf16x8 bq0, bf16x8 bq1,
                 f32x4* ctx, float& m_r, float& l_r,
                 int l16, int lhi, int lane, int swz){
  f32x4 s4[4] = {};
  #pragma unroll
  for (int nf = 0; nf < 4; ++nf){
    bf16x8 ak0 = *(const bf16x8*)&Ksb[(nf*16 + l16)*64 + ((lhi*8) ^ swz)];
    bf16x8 ak1 = *(const bf16x8*)&Ksb[(nf*16 + l16)*64 + ((32 + lhi*8) ^ swz)];
    s4[nf] = mfma16(ak0, bq0, s4[nf]);
    s4[nf] = mfma16(ak1, bq1, s4[nf]);
  }

  if (t == qt){
    #pragma unroll
    for (int nf = 0; nf < 4; ++nf)
      #pragma unroll
      for (int r = 0; r < 4; ++r){
        int kc = t*64 + nf*16 + lhi*4 + r;
        if (kc > q_abs) s4[nf][r] = -1.0e30f;
      }
  }

  float mt = fmaxf(
      fmaxf(fmaxf(fmaxf(s4[0][0],s4[0][1]), fmaxf(s4[0][2],s4[0][3])),
            fmaxf(fmaxf(s4[1][0],s4[1][1]), fmaxf(s4[1][2],s4[1][3]))),
      fmaxf(fmaxf(fmaxf(s4[2][0],s4[2][1]), fmaxf(s4[2][2],s4[2][3])),
            fmaxf(fmaxf(s4[3][0],s4[3][1]), fmaxf(s4[3][2],s4[3][3]))));
  mt = fmaxf(mt, __shfl_xor(mt, 16));
  mt = fmaxf(mt, __shfl_xor(mt, 32));

  if (!__all(mt <= m_r + THR)){
    float mn = fmaxf(m_r, mt);
    float sf = fexp2(m_r - mn);
    m_r = mn;
    l_r *= sf;
    float sfb[4];
    #pragma unroll
    for (int r = 0; r < 4; ++r)
      sfb[r] = __shfl(sf, (lane >> 4)*4 + r);
    #pragma unroll
    for (int dkf = 0; dkf < 4; ++dkf)
      #pragma unroll
      for (int r = 0; r < 4; ++r)
        ctx[dkf][r] *= sfb[r];
  }

  float lt = 0.f;
  u16* prow = PsW + l16*PLD;
  #pragma unroll
  for (int nf = 0; nf < 4; ++nf){
    float p0 = fexp2(s4[nf][0] - m_r);
    float p1 = fexp2(s4[nf][1] - m_r);
    float p2 = fexp2(s4[nf][2] - m_r);
    float p3 = fexp2(s4[nf][3] - m_r);
    lt += (p0 + p1) + (p2 + p3);
    unsigned w0 = __builtin_amdgcn_perm(__builtin_bit_cast(unsigned, p1),
                                        __builtin_bit_cast(unsigned, p0), 0x07060302u);
    unsigned w1 = __builtin_amdgcn_perm(__builtin_bit_cast(unsigned, p3),
                                        __builtin_bit_cast(unsigned, p2), 0x07060302u);
    u32x2 wp = {w0, w1};
    *(u32x2*)&prow[nf*16 + lhi*4] = wp;
  }
  lt += __shfl_xor(lt, 16);
  lt += __shfl_xor(lt, 32);
  l_r += lt;
}

DEV void pv_tile(const u16* __restrict__ Vsb, const u16* __restrict__ PsW,
                 f32x4* ctx, int l16, int lhi, int swz){
  const u16* prow = PsW + l16*PLD;
  __builtin_amdgcn_s_setprio(1);
  #pragma unroll
  for (int ks = 0; ks < 2; ++ks){
    bf16x8 pa = *(const bf16x8*)&prow[ks*32 + lhi*8];
    #pragma unroll
    for (int dkf = 0; dkf < 4; ++dkf){
      bf16x8 vb = *(const bf16x8*)&Vsb[(dkf*16 + l16)*64 + ((ks*32 + lhi*8) ^ swz)];
      ctx[dkf] = mfma16(pa, vb, ctx[dkf]);
    }
  }
  __builtin_amdgcn_s_setprio(0);
}

__global__ __launch_bounds__(256) void attn_k(const u16* __restrict__ Q,
                                              const u16* __restrict__ K,
                                              const u16* __restrict__ Vt,
                                              u16* __restrict__ CTX){
  __shared__ u16 Ks[2][64*64];
  __shared__ u16 Vs[2][64*64];
  __shared__ u16 Ps[4][2][16*PLD];
  const int tid  = threadIdx.x;
  const int lane = tid & 63, w = tid >> 6;
  const int l16 = lane & 15, lhi = lane >> 4;
  const int f  = blockIdx.x;
  const int bh = f & 31;
  const int qt = 31 - (f >> 5);
  const size_t base = (size_t)bh * 2048 * 64;
  const u16* Qb = Q  + base;
  const u16* Kb = K  + base;
  const u16* Vb = Vt + base;
  const int b = bh >> 4, h = bh & 15;

  const int s0 = tid, s1 = tid + 256;
  const int r0 = s0 >> 3, c0 = ((s0 & 7) ^ (r0 & 7))*8;
  const int r1 = s1 >> 3, c1 = ((s1 & 7) ^ (r1 & 7))*8;
  const u16* Ksrc0 = Kb + r0*64 + c0;
  const u16* Ksrc1 = Kb + r1*64 + c1;
  const u16* Vsrc0 = Vb + (size_t)r0*2048 + c0;
  const u16* Vsrc1 = Vb + (size_t)r1*2048 + c1;
  const int swz = (l16 & 7)*8;

  const int q_abs = qt*64 + w*16 + l16;
  bf16x8 bq0 = *(const bf16x8*)&Qb[(size_t)q_abs*64 + lhi*8];
  bf16x8 bq1 = *(const bf16x8*)&Qb[(size_t)q_abs*64 + 32 + lhi*8];

  f32x4 ctx[4] = {};
  float m_r = -3.0e38f, l_r = 0.f;
  u16* Ps0 = &Ps[w][0][0];
  u16* Ps1 = &Ps[w][1][0];

  gload16(Ksrc0, &Ks[0][s0*8]);  gload16(Ksrc1, &Ks[0][s1*8]);
  gload16(Vsrc0, &Vs[0][s0*8]);  gload16(Vsrc1, &Vs[0][s1*8]);
  __syncthreads();

  const int nt = qt + 1;
  for (int t = 0; t < nt; ++t){
    const int pb = t & 1;
    u16* PsC = pb ? Ps1 : Ps0;
    u16* PsP = pb ? Ps0 : Ps1;
    if (t + 1 < nt){
      gload16(Ksrc0 + (t+1)*4096, &Ks[pb^1][s0*8]);
      gload16(Ksrc1 + (t+1)*4096, &Ks[pb^1][s1*8]);
    }
    sm_tile(t, qt, q_abs, Ks[pb], PsC, bq0, bq1, ctx, m_r, l_r, l16, lhi, lane, swz);
    if (t > 0)
      pv_tile(Vs[pb^1], PsP, ctx, l16, lhi, swz);
    __syncthreads();
    if (t + 1 < nt){
      gload16(Vsrc0 + (size_t)(t+1)*64, &Vs[pb^1][s0*8]);
      gload16(Vsrc1 + (size_t)(t+1)*64, &Vs[pb^1][s1*8]);
    }
  }
  pv_tile(Vs[(nt-1)&1], (nt-1)&1 ? Ps1 : Ps0, ctx, l16, lhi, swz);

  float lf[4];
  #pragma unroll
  for (int r = 0; r < 4; ++r)
    lf[r] = __shfl(l_r, (lane >> 4)*4 + r);
  #pragma unroll
  for (int dkf = 0; dkf < 4; ++dkf)
    #pragma unroll
    for (int r = 0; r < 4; ++r){
      int q = qt*64 + w*16 + lhi*4 + r;
      CTX[((size_t)(b*2048 + q))*1024 + h*64 + dkf*16 + l16] = f2bf(ctx[dkf][r] / lf[r]);
    }
}

// ------------------------------------------------------------------
extern "C" void kernel_launch(void* const* d_in, const int* in_sizes, int n_in,
                              void* d_out, int out_size, void* d_ws, size_t ws_size,
                              hipStream_t stream){
  const float* q  = (const float*)d_in[0];
  const float* k  = (const float*)d_in[1];
  const float* v  = (const float*)d_in[2];
  const float* Wq = (const float*)d_in[4];  const float* bq = (const float*)d_in[5];
  const float* Wk = (const float*)d_in[6];  const float* bk = (const float*)d_in[7];
  const float* Wv = (const float*)d_in[8];  const float* bv = (const float*)d_in[9];
  const float* Wo = (const float*)d_in[10]; const float* bo = (const float*)d_in[11];
  float* out = (float*)d_out;
  dim3 blk(256);

  u16* Wqb = (u16*)d_ws;
  u16* Wkb = Wqb + 1048576;
  u16* Wvb = Wkb + 1048576;
  u16* Wob = Wvb + 1048576;
  u16* Xqb = Wob + 1048576;
  u16* Xkb = Xqb + 4194304;
  u16* Xvb = Xkb + 4194304;
  u16* Qw  = Xvb + 4194304;
  u16* Kw  = Qw + 4194304;
  u16* Vw  = Kw + 4194304;             // V^T [B,H,64,N]
  u16* Cw  = Xqb;                      // reuse: Xq dead after QKV GEMM

  cvt_k<<<dim3(512, 7), blk, 0, stream>>>(q, k, v, Wq, Wk, Wv, Wo,
                                          Xqb, Xkb, Xvb, Wqb, Wkb, Wvb, Wob);
  // z==2: A=Wv, B=Xv (swapped) -> V^T
  gemm_bt<<<dim3(8, 32, 3), blk, 0, stream>>>(
      Xqb, Xkb, Wvb, Wqb, Wkb, Xvb, bq, bk, bv, Qw, Kw, Vw);
  attn_k<<<dim3(1024), blk, 0, stream>>>(Qw, Kw, Vw, Cw);
  gemm_o64<<<dim3(8, 64), blk, 0, stream>>>(Cw, Wob, bo, out);
}

// Round 13
// 120.467 us; speedup vs baseline: 1.1229x; 1.0886x over previous
//
#include <hip/hip_runtime.h>
#include <hip/hip_bf16.h>

typedef __attribute__((ext_vector_type(4))) float f32x4;
typedef __attribute__((ext_vector_type(8))) __bf16 bf16x8;
typedef __attribute__((ext_vector_type(8))) unsigned short u16x8;
typedef __attribute__((ext_vector_type(4))) unsigned short u16x4;
typedef __attribute__((ext_vector_type(2))) unsigned int u32x2;
typedef unsigned short u16;

#define DEV static __device__ __forceinline__

DEV u16 f2bf(float f){
  unsigned u = __builtin_bit_cast(unsigned, f);
  u += 0x7fff + ((u >> 16) & 1);            // RNE
  return (u16)(u >> 16);
}

DEV f32x4 mfma16(bf16x8 a, bf16x8 b, f32x4 c){
  return __builtin_amdgcn_mfma_f32_16x16x32_bf16(a, b, c, 0, 0, 0);
}

DEV void gload16(const void* g, void* l){
  __builtin_amdgcn_global_load_lds((const __attribute__((address_space(1))) void*)g,
                                   (__attribute__((address_space(3))) void*)l,
                                   16, 0, 0);
}

DEV float fexp2(float x){
#if __has_builtin(__builtin_amdgcn_exp2f)
  return __builtin_amdgcn_exp2f(x);
#else
  float r; asm("v_exp_f32 %0, %1" : "=v"(r) : "v"(x)); return r;
#endif
}

#define SCL 0.18033688011f   /* 0.125 * log2(e) */
#define THR 11.0f            /* defer-max threshold (log2 units) */
#define PLD 72               /* P row stride in u16 */

// ------------------------------------------------------------------
// fp32 -> bf16 conversion: y 0-2 = X (4096x1024), y 3-6 = W (1024x1024).
// ------------------------------------------------------------------
__global__ __launch_bounds__(256) void cvt_k(
    const float* __restrict__ s0, const float* __restrict__ s1,
    const float* __restrict__ s2, const float* __restrict__ s3,
    const float* __restrict__ s4, const float* __restrict__ s5,
    const float* __restrict__ s6,
    u16* __restrict__ d0, u16* __restrict__ d1, u16* __restrict__ d2,
    u16* __restrict__ d3, u16* __restrict__ d4, u16* __restrict__ d5,
    u16* __restrict__ d6){
  const int y = blockIdx.y;
  const float* __restrict__ s = y==0?s0:y==1?s1:y==2?s2:y==3?s3:y==4?s4:y==5?s5:s6;
  u16* __restrict__ d         = y==0?d0:y==1?d1:y==2?d2:y==3?d3:y==4?d4:y==5?d5:d6;
  const int n8 = (y < 3) ? (4096*1024/8) : (1024*1024/8);
  for (int i = blockIdx.x*256 + threadIdx.x; i < n8; i += gridDim.x*256){
    f32x4 a = *(const f32x4*)&s[(size_t)i*8];
    f32x4 b = *(const f32x4*)&s[(size_t)i*8 + 4];
    u16x8 h;
    #pragma unroll
    for (int j = 0; j < 4; ++j){ h[j] = f2bf(a[j]); h[j+4] = f2bf(b[j]); }
    *(u16x8*)&d[(size_t)i*8] = h;
  }
}

// ------------------------------------------------------------------
// QKV GEMM: exact r9 structure (128x128 tile, BK=32, linear LDS,
// single buffer, 2 barriers/K-step) + XCD-grouped block decode:
// the 8 blocks sharing an A-panel land on one XCD's L2.
// z<2: C = X@W^T -> [B,H,N,64] (z==0 scaled by SCL);
// z==2: A=Wv, B=Xv -> V^T [B,H,64,N].
// ------------------------------------------------------------------
__global__ __launch_bounds__(256) void gemm_bt(
    const u16* __restrict__ A0, const u16* __restrict__ A1, const u16* __restrict__ A2,
    const u16* __restrict__ B0, const u16* __restrict__ B1, const u16* __restrict__ B2,
    const float* __restrict__ e0, const float* __restrict__ e1, const float* __restrict__ e2,
    u16* __restrict__ C0, u16* __restrict__ C1, u16* __restrict__ C2){
  __shared__ u16 As[128*32];
  __shared__ u16 Bs[128*32];

  // XCD-grouped bijective decode: 768 = 8 XCD * 12 panels * 8 bn.
  const int f = blockIdx.x;
  const int xc = f & 7, g = f >> 3;
  const int p  = xc*12 + (g >> 3);      // panel 0..95  ({z, bm32})
  const int bn8 = g & 7;
  const int z = p >> 5, bm32 = p & 31;
  const bool vt = (z == 2);
  const int bm = vt ? bn8 : bm32;
  const int bn = vt ? bm32 : bn8;

  const u16* __restrict__ A    = z==0 ? A0 : z==1 ? A1 : A2;
  const u16* __restrict__ Bw   = z==0 ? B0 : z==1 ? B1 : B2;
  const float* __restrict__ bias = z==0 ? e0 : z==1 ? e1 : e2;
  u16* __restrict__ C          = z==0 ? C0 : z==1 ? C1 : C2;
  const float qs = (z == 0) ? SCL : 1.0f;

  const int tid  = threadIdx.x;
  const int lane = tid & 63, w = tid >> 6;
  const int wr = w >> 1, wc = w & 1;
  const int l16 = lane & 15, lhi = lane >> 4;

  const int srow = w*16 + (lane >> 2);
  const int scol = (lane & 3)*8;
  const u16* Asrc = A  + (size_t)(bm*128 + srow)*1024 + scol;
  const u16* Bsrc = Bw + (size_t)(bn*128 + srow)*1024 + scol;
  u16* Adst0 = As + w*512;
  u16* Bdst0 = Bs + w*512;

  f32x4 acc[4][4] = {};

  for (int k0 = 0; k0 < 1024; k0 += 32){
    __syncthreads();
    gload16(Asrc + k0,             Adst0);
    gload16(Asrc + 64*1024 + k0,   Adst0 + 2048);
    gload16(Bsrc + k0,             Bdst0);
    gload16(Bsrc + 64*1024 + k0,   Bdst0 + 2048);
    __syncthreads();

    bf16x8 af[4], bfr[4];
    #pragma unroll
    for (int mi = 0; mi < 4; ++mi)
      af[mi] = *(const bf16x8*)&As[(wr*64 + mi*16 + l16)*32 + lhi*8];
    #pragma unroll
    for (int nf = 0; nf < 4; ++nf)
      bfr[nf] = *(const bf16x8*)&Bs[(wc*64 + nf*16 + l16)*32 + lhi*8];
    #pragma unroll
    for (int mi = 0; mi < 4; ++mi)
      #pragma unroll
      for (int nf = 0; nf < 4; ++nf)
        acc[mi][nf] = mfma16(af[mi], bfr[nf], acc[mi][nf]);
  }

  #pragma unroll
  for (int mi = 0; mi < 4; ++mi){
    #pragma unroll
    for (int nf = 0; nf < 4; ++nf){
      int row0 = bm*128 + wr*64 + mi*16 + lhi*4;
      int col  = bn*128 + wc*64 + nf*16 + l16;
      float bc = bias[col];
      #pragma unroll
      for (int r = 0; r < 4; ++r){
        int row = row0 + r;
        float val = (acc[mi][nf][r] + (vt ? bias[row] : bc)) * qs;
        if (!vt){
          int b = row >> 11, n = row & 2047;
          int h = col >> 6,  dk = col & 63;
          C[(((size_t)(b*16 + h))*2048 + n)*64 + dk] = f2bf(val);
        } else {
          int h = row >> 6,  dk = row & 63;
          int b = col >> 11, n = col & 2047;
          C[(((size_t)(b*16 + h))*64 + dk)*2048 + n] = f2bf(val);
        }
      }
    }
  }
}

// ------------------------------------------------------------------
// O-projection GEMM: 64x128 tile, grid (8,64), r9 2-barrier form.
// ------------------------------------------------------------------
__global__ __launch_bounds__(256) void gemm_o64(const u16* __restrict__ A,
                                                const u16* __restrict__ Bw,
                                                const float* __restrict__ bias,
                                                float* __restrict__ C){
  __shared__ u16 As[64*32];
  __shared__ u16 Bs[128*32];
  const int tid  = threadIdx.x;
  const int lane = tid & 63, w = tid >> 6;
  const int wr = w >> 1, wc = w & 1;
  const int l16 = lane & 15, lhi = lane >> 4;
  const int bm = blockIdx.y, bn = blockIdx.x;

  const int srow = w*16 + (lane >> 2);
  const int scol = (lane & 3)*8;
  const u16* Asrc = A  + (size_t)(bm*64  + srow)*1024 + scol;
  const u16* Bsrc = Bw + (size_t)(bn*128 + srow)*1024 + scol;
  u16* Adst0 = As + w*512;
  u16* Bdst0 = Bs + w*512;

  f32x4 acc[2][4] = {};

  for (int k0 = 0; k0 < 1024; k0 += 32){
    __syncthreads();
    gload16(Asrc + k0,             Adst0);
    gload16(Bsrc + k0,             Bdst0);
    gload16(Bsrc + 64*1024 + k0,   Bdst0 + 2048);
    __syncthreads();

    bf16x8 af[2], bfr[4];
    #pragma unroll
    for (int mi = 0; mi < 2; ++mi)
      af[mi] = *(const bf16x8*)&As[(wr*32 + mi*16 + l16)*32 + lhi*8];
    #pragma unroll
    for (int nf = 0; nf < 4; ++nf)
      bfr[nf] = *(const bf16x8*)&Bs[(wc*64 + nf*16 + l16)*32 + lhi*8];
    #pragma unroll
    for (int mi = 0; mi < 2; ++mi)
      #pragma unroll
      for (int nf = 0; nf < 4; ++nf)
        acc[mi][nf] = mfma16(af[mi], bfr[nf], acc[mi][nf]);
  }

  #pragma unroll
  for (int mi = 0; mi < 2; ++mi){
    #pragma unroll
    for (int nf = 0; nf < 4; ++nf){
      int row0 = bm*64 + wr*32 + mi*16 + lhi*4;
      int col  = bn*128 + wc*64 + nf*16 + l16;
      float bv = bias[col];
      #pragma unroll
      for (int r = 0; r < 4; ++r)
        C[(size_t)(row0 + r)*1024 + col] = acc[mi][nf][r] + bv;
    }
  }
}

// ------------------------------------------------------------------
// Flash attention, 8 waves / 128 q-rows per block, software-pipelined:
//   stageK(t+1) ; sm(t) ; pv(t-1) ; barrier ; stageV(t+1)
// Per-wave code identical to r9; KV staging + barriers per q-row halve.
// Causal: per-wave diagonal tile tdiag = 2*qt + (w>>2); tiles beyond
// it are fully masked (contribute 0, correct).
// ------------------------------------------------------------------
DEV void sm_tile(int t, int tdiag, int q_abs,
                 const u16* __restrict__ Ksb, u16* __restrict__ PsW,
                 bf16x8 bq0, bf16x8 bq1,
                 f32x4* ctx, float& m_r, float& l_r,
                 int l16, int lhi, int lane, int swz){
  f32x4 s4[4] = {};
  #pragma unroll
  for (int nf = 0; nf < 4; ++nf){
    bf16x8 ak0 = *(const bf16x8*)&Ksb[(nf*16 + l16)*64 + ((lhi*8) ^ swz)];
    bf16x8 ak1 = *(const bf16x8*)&Ksb[(nf*16 + l16)*64 + ((32 + lhi*8) ^ swz)];
    s4[nf] = mfma16(ak0, bq0, s4[nf]);
    s4[nf] = mfma16(ak1, bq1, s4[nf]);
  }

  if (t >= tdiag){                  // diagonal or fully-masked tile
    #pragma unroll
    for (int nf = 0; nf < 4; ++nf)
      #pragma unroll
      for (int r = 0; r < 4; ++r){
        int kc = t*64 + nf*16 + lhi*4 + r;
        if (kc > q_abs) s4[nf][r] = -1.0e30f;
      }
  }

  float mt = fmaxf(
      fmaxf(fmaxf(fmaxf(s4[0][0],s4[0][1]), fmaxf(s4[0][2],s4[0][3])),
            fmaxf(fmaxf(s4[1][0],s4[1][1]), fmaxf(s4[1][2],s4[1][3]))),
      fmaxf(fmaxf(fmaxf(s4[2][0],s4[2][1]), fmaxf(s4[2][2],s4[2][3])),
            fmaxf(fmaxf(s4[3][0],s4[3][1]), fmaxf(s4[3][2],s4[3][3]))));
  mt = fmaxf(mt, __shfl_xor(mt, 16));
  mt = fmaxf(mt, __shfl_xor(mt, 32));

  if (!__all(mt <= m_r + THR)){
    float mn = fmaxf(m_r, mt);
    float sf = fexp2(m_r - mn);
    m_r = mn;
    l_r *= sf;
    float sfb[4];
    #pragma unroll
    for (int r = 0; r < 4; ++r)
      sfb[r] = __shfl(sf, (lane >> 4)*4 + r);
    #pragma unroll
    for (int dkf = 0; dkf < 4; ++dkf)
      #pragma unroll
      for (int r = 0; r < 4; ++r)
        ctx[dkf][r] *= sfb[r];
  }

  float lt = 0.f;
  u16* prow = PsW + l16*PLD;
  #pragma unroll
  for (int nf = 0; nf < 4; ++nf){
    float p0 = fexp2(s4[nf][0] - m_r);
    float p1 = fexp2(s4[nf][1] - m_r);
    float p2 = fexp2(s4[nf][2] - m_r);
    float p3 = fexp2(s4[nf][3] - m_r);
    lt += (p0 + p1) + (p2 + p3);
    unsigned w0 = __builtin_amdgcn_perm(__builtin_bit_cast(unsigned, p1),
                                        __builtin_bit_cast(unsigned, p0), 0x07060302u);
    unsigned w1 = __builtin_amdgcn_perm(__builtin_bit_cast(unsigned, p3),
                                        __builtin_bit_cast(unsigned, p2), 0x07060302u);
    u32x2 wp = {w0, w1};
    *(u32x2*)&prow[nf*16 + lhi*4] = wp;
  }
  lt += __shfl_xor(lt, 16);
  lt += __shfl_xor(lt, 32);
  l_r += lt;
}

DEV void pv_tile(const u16* __restrict__ Vsb, const u16* __restrict__ PsW,
                 f32x4* ctx, int l16, int lhi, int swz){
  const u16* prow = PsW + l16*PLD;
  __builtin_amdgcn_s_setprio(1);
  #pragma unroll
  for (int ks = 0; ks < 2; ++ks){
    bf16x8 pa = *(const bf16x8*)&prow[ks*32 + lhi*8];
    #pragma unroll
    for (int dkf = 0; dkf < 4; ++dkf){
      bf16x8 vb = *(const bf16x8*)&Vsb[(dkf*16 + l16)*64 + ((ks*32 + lhi*8) ^ swz)];
      ctx[dkf] = mfma16(pa, vb, ctx[dkf]);
    }
  }
  __builtin_amdgcn_s_setprio(0);
}

__global__ __launch_bounds__(512) void attn_k(const u16* __restrict__ Q,
                                              const u16* __restrict__ K,
                                              const u16* __restrict__ Vt,
                                              u16* __restrict__ CTX){
  __shared__ u16 Ks[2][64*64];       // 16 KB
  __shared__ u16 Vs[2][64*64];       // 16 KB
  __shared__ u16 Ps[8][2][16*PLD];   // 36 KB
  const int tid  = threadIdx.x;
  const int lane = tid & 63, w = tid >> 6;       // w in 0..7
  const int l16 = lane & 15, lhi = lane >> 4;
  const int f  = blockIdx.x;                     // 512 blocks
  const int bh = f & 31;
  const int qt = 15 - (f >> 5);                  // longest-first, 128-row tiles
  const size_t base = (size_t)bh * 2048 * 64;
  const u16* Qb = Q  + base;
  const u16* Kb = K  + base;
  const u16* Vb = Vt + base;                     // [dk=64][n=2048]
  const int b = bh >> 4, h = bh & 15;

  // staging: 1 slot/thread each for K and V
  const int s0 = tid;
  const int r0 = s0 >> 3, c0 = ((s0 & 7) ^ (r0 & 7))*8;
  const u16* Ksrc0 = Kb + r0*64 + c0;            // +t*4096
  const u16* Vsrc0 = Vb + (size_t)r0*2048 + c0;  // +t*64
  const int swz = (l16 & 7)*8;

  const int q_abs = qt*128 + w*16 + l16;
  const int tdiag = 2*qt + (w >> 2);
  bf16x8 bq0 = *(const bf16x8*)&Qb[(size_t)q_abs*64 + lhi*8];
  bf16x8 bq1 = *(const bf16x8*)&Qb[(size_t)q_abs*64 + 32 + lhi*8];

  f32x4 ctx[4] = {};
  float m_r = -3.0e38f, l_r = 0.f;
  u16* Ps0 = &Ps[w][0][0];
  u16* Ps1 = &Ps[w][1][0];

  gload16(Ksrc0, &Ks[0][s0*8]);
  gload16(Vsrc0, &Vs[0][s0*8]);
  __syncthreads();

  const int nt = 2*qt + 2;
  for (int t = 0; t < nt; ++t){
    const int pb = t & 1;
    u16* PsC = pb ? Ps1 : Ps0;
    u16* PsP = pb ? Ps0 : Ps1;
    if (t + 1 < nt)
      gload16(Ksrc0 + (t+1)*4096, &Ks[pb^1][s0*8]);
    sm_tile(t, tdiag, q_abs, Ks[pb], PsC, bq0, bq1, ctx, m_r, l_r, l16, lhi, lane, swz);
    if (t > 0)
      pv_tile(Vs[pb^1], PsP, ctx, l16, lhi, swz);
    __syncthreads();
    if (t + 1 < nt)
      gload16(Vsrc0 + (size_t)(t+1)*64, &Vs[pb^1][s0*8]);
  }
  pv_tile(Vs[(nt-1)&1], (nt-1)&1 ? Ps1 : Ps0, ctx, l16, lhi, swz);

  float lf[4];
  #pragma unroll
  for (int r = 0; r < 4; ++r)
    lf[r] = __shfl(l_r, (lane >> 4)*4 + r);
  #pragma unroll
  for (int dkf = 0; dkf < 4; ++dkf)
    #pragma unroll
    for (int r = 0; r < 4; ++r){
      int q = qt*128 + w*16 + lhi*4 + r;
      CTX[((size_t)(b*2048 + q))*1024 + h*64 + dkf*16 + l16] = f2bf(ctx[dkf][r] / lf[r]);
    }
}

// ------------------------------------------------------------------
extern "C" void kernel_launch(void* const* d_in, const int* in_sizes, int n_in,
                              void* d_out, int out_size, void* d_ws, size_t ws_size,
                              hipStream_t stream){
  const float* q  = (const float*)d_in[0];
  const float* k  = (const float*)d_in[1];
  const float* v  = (const float*)d_in[2];
  const float* Wq = (const float*)d_in[4];  const float* bq = (const float*)d_in[5];
  const float* Wk = (const float*)d_in[6];  const float* bk = (const float*)d_in[7];
  const float* Wv = (const float*)d_in[8];  const float* bv = (const float*)d_in[9];
  const float* Wo = (const float*)d_in[10]; const float* bo = (const float*)d_in[11];
  float* out = (float*)d_out;

  u16* Wqb = (u16*)d_ws;
  u16* Wkb = Wqb + 1048576;
  u16* Wvb = Wkb + 1048576;
  u16* Wob = Wvb + 1048576;
  u16* Xqb = Wob + 1048576;
  u16* Xkb = Xqb + 4194304;
  u16* Xvb = Xkb + 4194304;
  u16* Qw  = Xvb + 4194304;
  u16* Kw  = Qw + 4194304;
  u16* Vw  = Kw + 4194304;             // V^T [B,H,64,N]
  u16* Cw  = Xqb;                      // reuse: Xq dead after QKV GEMM

  cvt_k<<<dim3(512, 7), dim3(256), 0, stream>>>(q, k, v, Wq, Wk, Wv, Wo,
                                                Xqb, Xkb, Xvb, Wqb, Wkb, Wvb, Wob);
  // z==2: A=Wv, B=Xv (swapped) -> V^T
  gemm_bt<<<dim3(768), dim3(256), 0, stream>>>(
      Xqb, Xkb, Wvb, Wqb, Wkb, Xvb, bq, bk, bv, Qw, Kw, Vw);
  attn_k<<<dim3(512), dim3(512), 0, stream>>>(Qw, Kw, Vw, Cw);
  gemm_o64<<<dim3(8, 64), dim3(256), 0, stream>>>(Cw, Wob, bo, out);
}